// Round 1
// baseline (343.025 us; speedup 1.0000x reference)
//
#include <hip/hip_runtime.h>
#include <hip/hip_bf16.h>
#include <math.h>

// Problem constants (B,C,H,W = 16,512,64,64; K=32)
#define BB 16
#define CC 512
#define NN 4096   // H*W
#define KK 32

// ws layout (floats):
// [0, 16384)                cwt  (C x K)  codewords transposed, c-major
// [16384, 16416)            c2   (K)      sum_c cw^2
// [16416, 16928)            asum (B*K)    sum_n A[b,n,k]
// [16928, 16928 + B*K*N)    A    (B,K,N)  softmax weights, k-major rows over n

// ---------------- K0: prep (transpose cw, c2, zero asum) ----------------
__global__ void prep_kernel(const float* __restrict__ cw, float* __restrict__ cwt,
                            float* __restrict__ c2, float* __restrict__ asum) {
  int gid = blockIdx.x * blockDim.x + threadIdx.x;
  if (gid < BB * KK) asum[gid] = 0.0f;
  for (int idx = gid; idx < KK * CC; idx += gridDim.x * blockDim.x) {
    int c = idx >> 5, k = idx & 31;
    cwt[idx] = cw[k * CC + c];
  }
  __shared__ float c2p[KK][8];
  if (blockIdx.x == 0) {
    int k = threadIdx.x >> 3, j = threadIdx.x & 7;
    const float* row = cw + k * CC + j * 64;
    float s = 0.f;
    for (int i = 0; i < 64; ++i) s = fmaf(row[i], row[i], s);
    c2p[k][j] = s;
    __syncthreads();
    if (threadIdx.x < KK) {
      float t = 0.f;
      for (int j2 = 0; j2 < 8; ++j2) t += c2p[threadIdx.x][j2];
      c2[threadIdx.x] = t;
    }
  }
}

// ---------------- K1: logits + softmax -> A, asum ----------------
// grid 256 = 16 b x 16 chunks of 256 positions; block 256 threads, 1 pos each.
__global__ __launch_bounds__(256) void logits_kernel(
    const float* __restrict__ x, const float* __restrict__ cwt,
    const float* __restrict__ c2, const float* __restrict__ scale,
    float* __restrict__ A, float* __restrict__ asum) {
  const int b = blockIdx.x >> 4;
  const int n = ((blockIdx.x & 15) << 8) + threadIdx.x;
  const float* xp = x + (size_t)b * CC * NN + n;

  float acc[KK];
#pragma unroll
  for (int k = 0; k < KK; ++k) acc[k] = 0.f;
  float x2 = 0.f;

  constexpr int G = 8;  // channel group; keeps register pressure sane
  float xv[G], xn[G];
#pragma unroll
  for (int j = 0; j < G; ++j) xv[j] = xp[(size_t)j * NN];

  for (int cg = 0; cg < CC; cg += G) {
    if (cg + G < CC) {
#pragma unroll
      for (int j = 0; j < G; ++j) xn[j] = xp[(size_t)(cg + G + j) * NN];
    }
#pragma unroll
    for (int j = 0; j < G; ++j) {
      float xvj = xv[j];
      x2 = fmaf(xvj, xvj, x2);
      const float* cwp = cwt + (cg + j) * KK;  // wave-uniform address -> s_load
#pragma unroll
      for (int k = 0; k < KK; ++k) acc[k] = fmaf(xvj, cwp[k], acc[k]);
    }
#pragma unroll
    for (int j = 0; j < G; ++j) xv[j] = xn[j];
  }

  // logits: scale_k * (x2 - 2*xc + c2_k); softmax over k
  float m = -INFINITY;
#pragma unroll
  for (int k = 0; k < KK; ++k) {
    float l = scale[k] * (x2 - 2.f * acc[k] + c2[k]);
    acc[k] = l;
    m = fmaxf(m, l);
  }
  float s = 0.f;
#pragma unroll
  for (int k = 0; k < KK; ++k) {
    float e = __expf(acc[k] - m);
    acc[k] = e;
    s += e;
  }
  float inv = 1.0f / s;
  float* Ab = A + ((size_t)b * KK) * NN + n;
#pragma unroll
  for (int k = 0; k < KK; ++k) {
    float a = acc[k] * inv;
    acc[k] = a;
    Ab[(size_t)k * NN] = a;  // coalesced per k
  }
  // wave-reduce per k, one atomicAdd per wave
#pragma unroll
  for (int k = 0; k < KK; ++k) {
    float v = acc[k];
    v += __shfl_xor(v, 1);
    v += __shfl_xor(v, 2);
    v += __shfl_xor(v, 4);
    v += __shfl_xor(v, 8);
    v += __shfl_xor(v, 16);
    v += __shfl_xor(v, 32);
    if ((threadIdx.x & 63) == 0) atomicAdd(&asum[b * KK + k], v);
  }
}

// ---------------- K2: encoded[b,k,c] = sum_n A*x - asum*cw ----------------
// grid 256 = 16 b x 16 c-chunks of 32; block 256 threads; thread owns 2k x 2c.
constexpr int NCH = 128;
__global__ __launch_bounds__(256) void agg_kernel(
    const float* __restrict__ x, const float* __restrict__ A,
    const float* __restrict__ asum, const float* __restrict__ cw,
    float* __restrict__ out) {
  const int b = blockIdx.x >> 4;
  const int c0 = (blockIdx.x & 15) << 5;
  const int tid = threadIdx.x;
  const int ks = tid & 15;   // k in {ks, ks+16}
  const int cs = tid >> 4;   // c in {cs, cs+16}

  constexpr int P = NCH + 4;  // pitch 132: 16B-aligned rows, bank stride 4
  __shared__ float Al[KK * P];
  __shared__ float Xl[32 * P];

  const int r = tid >> 3;          // staging row 0..31
  const int i4 = (tid & 7) * 4;    // staging col base

  const float* Arow = A + ((size_t)b * KK + r) * NN;
  const float* Xrow = x + ((size_t)b * CC + c0 + r) * NN;

  float acc00 = 0.f, acc01 = 0.f, acc10 = 0.f, acc11 = 0.f;

  for (int n0 = 0; n0 < NN; n0 += NCH) {
    __syncthreads();
#pragma unroll
    for (int j = 0; j < 4; ++j) {
      int col = i4 + j * 32;
      float4 av = *(const float4*)(Arow + n0 + col);
      float4 xvv = *(const float4*)(Xrow + n0 + col);
      *(float4*)&Al[r * P + col] = av;
      *(float4*)&Xl[r * P + col] = xvv;
    }
    __syncthreads();
#pragma unroll 4
    for (int nn = 0; nn < NCH; nn += 4) {
      float4 a0 = *(const float4*)&Al[ks * P + nn];
      float4 a1 = *(const float4*)&Al[(ks + 16) * P + nn];
      float4 x0 = *(const float4*)&Xl[cs * P + nn];
      float4 x1 = *(const float4*)&Xl[(cs + 16) * P + nn];
      acc00 = fmaf(a0.x, x0.x, fmaf(a0.y, x0.y, fmaf(a0.z, x0.z, fmaf(a0.w, x0.w, acc00))));
      acc01 = fmaf(a0.x, x1.x, fmaf(a0.y, x1.y, fmaf(a0.z, x1.z, fmaf(a0.w, x1.w, acc01))));
      acc10 = fmaf(a1.x, x0.x, fmaf(a1.y, x0.y, fmaf(a1.z, x0.z, fmaf(a1.w, x0.w, acc10))));
      acc11 = fmaf(a1.x, x1.x, fmaf(a1.y, x1.y, fmaf(a1.z, x1.z, fmaf(a1.w, x1.w, acc11))));
    }
  }

  const int k0 = ks, k1 = ks + 16;
  const int ca = c0 + cs, cb = c0 + cs + 16;
  const float as0 = asum[b * KK + k0];
  const float as1 = asum[b * KK + k1];
  out[((size_t)b * KK + k0) * CC + ca] = acc00 - as0 * cw[k0 * CC + ca];
  out[((size_t)b * KK + k0) * CC + cb] = acc01 - as0 * cw[k0 * CC + cb];
  out[((size_t)b * KK + k1) * CC + ca] = acc10 - as1 * cw[k1 * CC + ca];
  out[((size_t)b * KK + k1) * CC + cb] = acc11 - as1 * cw[k1 * CC + cb];
}

extern "C" void kernel_launch(void* const* d_in, const int* in_sizes, int n_in,
                              void* d_out, int out_size, void* d_ws, size_t ws_size,
                              hipStream_t stream) {
  const float* x = (const float*)d_in[0];      // (B,C,H,W) = (16,512,64,64)
  const float* cw = (const float*)d_in[1];     // (K,C) = (32,512)
  const float* scale = (const float*)d_in[2];  // (K,)
  float* out = (float*)d_out;                  // (B,K,C)
  float* ws = (float*)d_ws;

  float* cwt = ws;             // 16384
  float* c2 = ws + 16384;      // 32
  float* asum = ws + 16416;    // 512
  float* A = ws + 16928;       // B*K*N = 2097152

  prep_kernel<<<64, 256, 0, stream>>>(cw, cwt, c2, asum);
  logits_kernel<<<256, 256, 0, stream>>>(x, cwt, c2, scale, A, asum);
  agg_kernel<<<256, 256, 0, stream>>>(x, A, asum, cw, out);
}